// Round 1
// baseline (1268.151 us; speedup 1.0000x reference)
//
#include <hip/hip_runtime.h>
#include <stdint.h>

// Problem: M=8192 tokens, N=4096 out, K=4096 in. fp32 in/out.
#define M_DIM 8192
#define N_DIM 4096
#define K_DIM 4096

typedef __attribute__((ext_vector_type(8))) short short8;   // 8 bf16 = 4 VGPR (MFMA A/B frag)
typedef __attribute__((ext_vector_type(4))) float f32x4;    // MFMA C/D frag

// ---------- helpers ----------
__device__ __forceinline__ unsigned fkey(float f) {
  // monotone float->uint mapping (no NaNs in this problem)
  unsigned u = __float_as_uint(f);
  return (u & 0x80000000u) ? ~u : (u | 0x80000000u);
}
__device__ __forceinline__ float finv(unsigned k) {
  return __uint_as_float((k & 0x80000000u) ? (k ^ 0x80000000u) : ~k);
}
__device__ __forceinline__ unsigned short bf16_rne(float f) {
  unsigned u = __float_as_uint(f);
  unsigned r = u + 0x7FFFu + ((u >> 16) & 1u);
  return (unsigned short)(r >> 16);
}
__device__ __forceinline__ float bf16_to_f(unsigned short h) {
  return __uint_as_float(((unsigned)h) << 16);
}
__device__ __forceinline__ void async16(const unsigned short* g, unsigned short* l) {
  // global -> LDS direct, 16B/lane; LDS dest = wave-uniform base + lane*16
  __builtin_amdgcn_global_load_lds(
      (const __attribute__((address_space(1))) void*)g,
      (__attribute__((address_space(3))) void*)l, 16, 0, 0);
}

// ---------- 1. init stats ----------
// stats layout (uint32): [0]xmin [1]xmax [2]wmin [3]wmax [4]amin [5]amax (as fkey)
__global__ void init_kernel(unsigned* stats) {
  int i = threadIdx.x;
  if (i < 6) stats[i] = (i & 1) ? 0u : 0xFFFFFFFFu;
}

// ---------- 2. min/max reduction ----------
__global__ void minmax_kernel(const float* __restrict__ v, int n4, unsigned* __restrict__ mk) {
  const float4* v4 = (const float4*)v;
  int i0 = blockIdx.x * blockDim.x + threadIdx.x;
  int stride = gridDim.x * blockDim.x;
  float vmin = 3.4e38f, vmax = -3.4e38f;
  for (int i = i0; i < n4; i += stride) {
    float4 t = v4[i];
    vmin = fminf(vmin, fminf(fminf(t.x, t.y), fminf(t.z, t.w)));
    vmax = fmaxf(vmax, fmaxf(fmaxf(t.x, t.y), fmaxf(t.z, t.w)));
  }
  unsigned kmin = fkey(vmin), kmax = fkey(vmax);
  #pragma unroll
  for (int off = 32; off; off >>= 1) {
    unsigned t0 = __shfl_down(kmin, (unsigned)off, 64);
    unsigned t1 = __shfl_down(kmax, (unsigned)off, 64);
    kmin = kmin < t0 ? kmin : t0;
    kmax = kmax > t1 ? kmax : t1;
  }
  if ((threadIdx.x & 63) == 0) {
    atomicMin(&mk[0], kmin);
    atomicMax(&mk[1], kmax);
  }
}

// ---------- 3. scales/zps (bit-exact vs reference: (max-min)/255, zp=rint(qmin-min/scale)) ----------
__global__ void params1_kernel(const unsigned* __restrict__ stats, float* __restrict__ params) {
  float xmin = finv(stats[0]), xmax = finv(stats[1]);
  float xs = (xmax - xmin) / 255.0f;
  float xzp = rintf(0.0f - xmin / xs);        // quint8: qmin = 0
  float wmin = finv(stats[2]), wmax = finv(stats[3]);
  float ws = (wmax - wmin) / 255.0f;
  float wzp = rintf(-128.0f - wmin / ws);     // qint8: qmin = -128
  params[0] = xs; params[1] = xzp; params[2] = ws; params[3] = wzp;
}

// ---------- 4. quantize x -> bf16(q - zp)  (integer |.|<=256, exact in bf16) ----------
__global__ void quant_x_kernel(const float* __restrict__ x, const float* __restrict__ params,
                               unsigned short* __restrict__ Aq, int n4) {
  const float xs = params[0], xzp = params[1];
  const float4* x4 = (const float4*)x;
  ushort4* a4 = (ushort4*)Aq;
  int i0 = blockIdx.x * blockDim.x + threadIdx.x;
  int stride = gridDim.x * blockDim.x;
  for (int i = i0; i < n4; i += stride) {
    float4 t = x4[i];
    ushort4 o;
    o.x = bf16_rne(fminf(fmaxf(rintf(t.x / xs + xzp), 0.f), 255.f) - xzp);
    o.y = bf16_rne(fminf(fmaxf(rintf(t.y / xs + xzp), 0.f), 255.f) - xzp);
    o.z = bf16_rne(fminf(fmaxf(rintf(t.z / xs + xzp), 0.f), 255.f) - xzp);
    o.w = bf16_rne(fminf(fmaxf(rintf(t.w / xs + xzp), 0.f), 255.f) - xzp);
    a4[i] = o;
  }
}

// ---------- 5. quantize/split w -> w_hi (bf16), w_lo (bf16 residual), bf16(q - zp) ----------
__global__ void quant_w_kernel(const float* __restrict__ w, const float* __restrict__ params,
                               unsigned short* __restrict__ Wh, unsigned short* __restrict__ Wl,
                               unsigned short* __restrict__ Wq, int n4) {
  const float ws = params[2], wzp = params[3];
  const float4* w4 = (const float4*)w;
  ushort4* h4 = (ushort4*)Wh;
  ushort4* l4 = (ushort4*)Wl;
  ushort4* q4 = (ushort4*)Wq;
  int i0 = blockIdx.x * blockDim.x + threadIdx.x;
  int stride = gridDim.x * blockDim.x;
  for (int i = i0; i < n4; i += stride) {
    float4 t = w4[i];
    ushort4 h, l, q;
    float v, hf;
    v = t.x; h.x = bf16_rne(v); hf = bf16_to_f(h.x); l.x = bf16_rne(v - hf);
    q.x = bf16_rne(fminf(fmaxf(rintf(v / ws + wzp), -128.f), 127.f) - wzp);
    v = t.y; h.y = bf16_rne(v); hf = bf16_to_f(h.y); l.y = bf16_rne(v - hf);
    q.y = bf16_rne(fminf(fmaxf(rintf(v / ws + wzp), -128.f), 127.f) - wzp);
    v = t.z; h.z = bf16_rne(v); hf = bf16_to_f(h.z); l.z = bf16_rne(v - hf);
    q.z = bf16_rne(fminf(fmaxf(rintf(v / ws + wzp), -128.f), 127.f) - wzp);
    v = t.w; h.w = bf16_rne(v); hf = bf16_to_f(h.w); l.w = bf16_rne(v - hf);
    q.w = bf16_rne(fminf(fmaxf(rintf(v / ws + wzp), -128.f), 127.f) - wzp);
    h4[i] = h; l4[i] = l; q4[i] = q;
  }
}

// ---------- 6. fused GEMM: act (hi+lo chains, min/max only) + out (q chain, stored) ----------
// m97 structure: 128x128 tile, BK=32, 4 waves (2x2) of 64x64, global_load_lds w=16.
// 16x16x32 bf16 MFMA. A frag: A[m=lane&15][k=(lane>>4)*8+j]; B frag same (B^T input);
// C/D: col=lane&15, row=(lane>>4)*4+reg.
__global__ __launch_bounds__(256, 2) void gemm_fused(
    const unsigned short* __restrict__ A,   // [8192][4096] bf16 (q_x - x_zp)
    const unsigned short* __restrict__ Bh,  // [4096][4096] bf16 hi(w)
    const unsigned short* __restrict__ Bl,  // [4096][4096] bf16 lo(w)
    const unsigned short* __restrict__ Bq,  // [4096][4096] bf16 (q_w - w_zp)
    const float* __restrict__ bias,
    const float* __restrict__ params,
    unsigned* __restrict__ stats,
    float* __restrict__ outp)               // [8192][4096] fp32 pre-requant
{
  __shared__ __align__(16) unsigned short sA[128 * 32];
  __shared__ __align__(16) unsigned short sBh[128 * 32];
  __shared__ __align__(16) unsigned short sBl[128 * 32];
  __shared__ __align__(16) unsigned short sBq[128 * 32];
  __shared__ unsigned s_red[2];

  const int tid = threadIdx.x;
  const int wave = tid >> 6;
  const int lane = tid & 63;
  const int bm = blockIdx.x >> 5;          // 64 row-blocks
  const int bn = blockIdx.x & 31;          // 32 col-blocks
  const int rowBase = bm * 128;
  const int colBase = bn * 128;
  const int wr = wave >> 1;                // 0..1
  const int wc = wave & 1;                 // 0..1

  if (tid == 0) { s_red[0] = 0xFFFFFFFFu; s_red[1] = 0u; }

  f32x4 acc_a[4][4];
  f32x4 acc_o[4][4];
  const f32x4 zero = {0.f, 0.f, 0.f, 0.f};
  #pragma unroll
  for (int i = 0; i < 4; ++i)
    #pragma unroll
    for (int j = 0; j < 4; ++j) { acc_a[i][j] = zero; acc_o[i][j] = zero; }

  const int lrow = lane >> 2;              // 0..15 (staging row within band)
  const int lcol = (lane & 3) * 8;         // 0,8,16,24 (staging k-chunk)
  const int arow = lane & 15;              // frag row/col
  const int kq = (lane >> 4) * 8;          // frag k-offset

  for (int kt = 0; kt < K_DIM; kt += 32) {
    #pragma unroll
    for (int b = 0; b < 2; ++b) {
      const int srow = b * 64 + wave * 16;
      const size_t aoff = (size_t)(rowBase + srow + lrow) * K_DIM + kt + lcol;
      const size_t boff = (size_t)(colBase + srow + lrow) * K_DIM + kt + lcol;
      const int loff = srow * 32 + lane * 8;
      async16(A + aoff, sA + loff);
      async16(Bh + boff, sBh + loff);
      async16(Bl + boff, sBl + loff);
      async16(Bq + boff, sBq + loff);
    }
    __syncthreads();

    short8 af[4];
    #pragma unroll
    for (int mi = 0; mi < 4; ++mi)
      af[mi] = *(const short8*)(sA + (wr * 64 + mi * 16 + arow) * 32 + kq);

    #pragma unroll
    for (int ni = 0; ni < 4; ++ni) {
      const int bo = (wc * 64 + ni * 16 + arow) * 32 + kq;
      short8 bh = *(const short8*)(sBh + bo);
      short8 bl = *(const short8*)(sBl + bo);
      short8 bq = *(const short8*)(sBq + bo);
      #pragma unroll
      for (int mi = 0; mi < 4; ++mi) {
        acc_a[mi][ni] = __builtin_amdgcn_mfma_f32_16x16x32_bf16(af[mi], bh, acc_a[mi][ni], 0, 0, 0);
        acc_a[mi][ni] = __builtin_amdgcn_mfma_f32_16x16x32_bf16(af[mi], bl, acc_a[mi][ni], 0, 0, 0);
        acc_o[mi][ni] = __builtin_amdgcn_mfma_f32_16x16x32_bf16(af[mi], bq, acc_o[mi][ni], 0, 0, 0);
      }
    }
    __syncthreads();
  }

  // epilogue: act = xs*acc_a + bias (min/max only); out = xs*ws*acc_o + bias (stored)
  const float xs = params[0];
  const float wsc = params[2];
  const float sw = xs * wsc;
  unsigned kmin = 0xFFFFFFFFu, kmax = 0u;

  #pragma unroll
  for (int ni = 0; ni < 4; ++ni) {
    const int col = colBase + wc * 64 + ni * 16 + arow;
    const float bv = bias[col];
    #pragma unroll
    for (int mi = 0; mi < 4; ++mi) {
      const int row0 = rowBase + wr * 64 + mi * 16 + (lane >> 4) * 4;
      #pragma unroll
      for (int r = 0; r < 4; ++r) {
        const float av = xs * acc_a[mi][ni][r] + bv;
        const float ov = sw * acc_o[mi][ni][r] + bv;
        const unsigned k = fkey(av);
        kmin = kmin < k ? kmin : k;
        kmax = kmax > k ? kmax : k;
        outp[(size_t)(row0 + r) * N_DIM + col] = ov;
      }
    }
  }

  #pragma unroll
  for (int off = 32; off; off >>= 1) {
    unsigned t0 = __shfl_down(kmin, (unsigned)off, 64);
    unsigned t1 = __shfl_down(kmax, (unsigned)off, 64);
    kmin = kmin < t0 ? kmin : t0;
    kmax = kmax > t1 ? kmax : t1;
  }
  __syncthreads();
  if (lane == 0) { atomicMin(&s_red[0], kmin); atomicMax(&s_red[1], kmax); }
  __syncthreads();
  if (tid == 0) { atomicMin(&stats[4], s_red[0]); atomicMax(&stats[5], s_red[1]); }
}

// ---------- 7. act scale/zp ----------
__global__ void params2_kernel(const unsigned* __restrict__ stats, float* __restrict__ params) {
  float amin = finv(stats[4]), amax = finv(stats[5]);
  float as = (amax - amin) / 255.0f;
  float azp = rintf(0.0f - amin / as);
  params[4] = as; params[5] = azp;
}

// ---------- 8. requantize out in place ----------
__global__ void requant_kernel(float* __restrict__ out, const float* __restrict__ params, int n4) {
  const float as = params[4], azp = params[5];
  float4* o4 = (float4*)out;
  int i0 = blockIdx.x * blockDim.x + threadIdx.x;
  int stride = gridDim.x * blockDim.x;
  for (int i = i0; i < n4; i += stride) {
    float4 t = o4[i];
    t.x = (fminf(fmaxf(rintf(t.x / as + azp), 0.f), 255.f) - azp) * as;
    t.y = (fminf(fmaxf(rintf(t.y / as + azp), 0.f), 255.f) - azp) * as;
    t.z = (fminf(fmaxf(rintf(t.z / as + azp), 0.f), 255.f) - azp) * as;
    t.w = (fminf(fmaxf(rintf(t.w / as + azp), 0.f), 255.f) - azp) * as;
    o4[i] = t;
  }
}

extern "C" void kernel_launch(void* const* d_in, const int* in_sizes, int n_in,
                              void* d_out, int out_size, void* d_ws, size_t ws_size,
                              hipStream_t stream) {
  const float* x = (const float*)d_in[0];      // [8192,4096]
  const float* w = (const float*)d_in[1];      // [4096,4096]
  const float* bias = (const float*)d_in[2];   // [4096]
  float* out = (float*)d_out;                  // [8192,4096]

  // workspace layout (needs ~168 MB)
  unsigned* stats = (unsigned*)d_ws;                                // 6 uints
  float* params = (float*)((char*)d_ws + 64);                       // 6 floats
  unsigned short* Aq = (unsigned short*)((char*)d_ws + 256);        // 8192*4096 bf16
  unsigned short* Wh = Aq + (size_t)M_DIM * K_DIM;                  // 4096*4096 bf16
  unsigned short* Wl = Wh + (size_t)N_DIM * K_DIM;
  unsigned short* Wq = Wl + (size_t)N_DIM * K_DIM;

  init_kernel<<<1, 64, 0, stream>>>(stats);
  minmax_kernel<<<1024, 256, 0, stream>>>(x, M_DIM * K_DIM / 4, stats + 0);
  minmax_kernel<<<512, 256, 0, stream>>>(w, N_DIM * K_DIM / 4, stats + 2);
  params1_kernel<<<1, 1, 0, stream>>>(stats, params);
  quant_x_kernel<<<2048, 256, 0, stream>>>(x, params, Aq, M_DIM * K_DIM / 4);
  quant_w_kernel<<<1024, 256, 0, stream>>>(w, params, Wh, Wl, Wq, N_DIM * K_DIM / 4);
  gemm_fused<<<(M_DIM / 128) * (N_DIM / 128), 256, 0, stream>>>(Aq, Wh, Wl, Wq, bias, params, stats, out);
  params2_kernel<<<1, 1, 0, stream>>>(stats, params);
  requant_kernel<<<2048, 256, 0, stream>>>(out, params, M_DIM * N_DIM / 4);
}